// Round 3
// baseline (51254.352 us; speedup 1.0000x reference)
//
#include <hip/hip_runtime.h>
#include <hip/hip_bf16.h>
#include <cstdint>
#include <cstddef>

#define BB 64
#define TT 512
#define DD 1024
#define HH 2048
#define GG 8192   // 4*H

typedef unsigned short u16;
typedef __attribute__((ext_vector_type(8))) short bf16x8;
typedef __attribute__((ext_vector_type(4))) float f32x4;

__device__ __forceinline__ u16 f2bf(float f) {
  union { float f; uint32_t u; } v; v.f = f;
  uint32_t r = v.u + 0x7FFFu + ((v.u >> 16) & 1u);  // RNE
  return (u16)(r >> 16);
}
__device__ __forceinline__ float bf2f(u16 h) {
  union { uint32_t u; float f; } v; v.u = ((uint32_t)h) << 16; return v.f;
}

__device__ __forceinline__ bf16x8 cvt8(const float* __restrict__ p) {
  float4 a = *(const float4*)p;
  float4 b = *(const float4*)(p + 4);
  bf16x8 r;
  r[0] = (short)f2bf(a.x); r[1] = (short)f2bf(a.y);
  r[2] = (short)f2bf(a.z); r[3] = (short)f2bf(a.w);
  r[4] = (short)f2bf(b.x); r[5] = (short)f2bf(b.y);
  r[6] = (short)f2bf(b.z); r[7] = (short)f2bf(b.w);
  return r;
}

// ---- preps ----
__global__ void conv_wih_kernel(const float* __restrict__ W, u16* __restrict__ Wb) {
  size_t idx = (size_t)blockIdx.x * blockDim.x + threadIdx.x;
  if (idx >= (size_t)GG * DD / 8) return;
  *(bf16x8*)(Wb + idx * 8) = cvt8(W + idx * 8);
}

// x: [B][T][D] fp32 -> xbT: [T][B][D] bf16
__global__ void conv_xT_kernel(const float* __restrict__ x, u16* __restrict__ xbT) {
  size_t idx = (size_t)blockIdx.x * blockDim.x + threadIdx.x;
  if (idx >= (size_t)BB * TT * DD / 8) return;
  const int col8 = (int)(idx & 127);
  const int row = (int)(idx >> 7);          // b*512 + t
  const int b = row >> 9, t = row & 511;
  bf16x8 v = cvt8(x + (size_t)row * DD + col8 * 8);
  *(bf16x8*)(xbT + ((size_t)t * BB + b) * DD + col8 * 8) = v;
}

// ======================= persistent LSTM =======================
// 256 WGs x 512 thr, 1 WG/CU (forced by 145 KB LDS). WG owns h cols j0..j0+7
// (32 gate rows). W_hh slice LDS-stationary; W_ih slice L2-resident; c in regs.
// Grid barrier: flag-array slots[256], one store per WG, 256 pollers per WG.
template<int XMODE>   // 1: x from xbT [T,B,D] bf16; 0: x fp32 [B,T,D] direct
__global__ __launch_bounds__(512, 1)
void lstm_persistent(const float* __restrict__ x, const u16* __restrict__ xbT,
                     const u16* __restrict__ wihb, const float* __restrict__ W_hh,
                     const float* __restrict__ b_ih, const float* __restrict__ b_hh,
                     u16* __restrict__ h0, u16* __restrict__ h1,
                     int* __restrict__ slots) {
  __shared__ u16 Wlds[64 * 2 * 64 * 8];   // 128 KB  [kb][which][lane][8]
  __shared__ float red[4 * 2 * 64 * 4];   // 8 KB
  __shared__ float gst[64 * 36];          // 9 KB (padded rows)

  const int tid = threadIdx.x;
  const int wave = tid >> 6, lane = tid & 63;
  const int m = wave & 3, khalf = wave >> 2;
  const int c = lane & 15, g = lane >> 4;
  const int wg = blockIdx.x, j0 = wg * 8;

  // ---- one-time: W_hh slice -> LDS in MFMA fragment order ----
  {
    const int r = tid >> 4;              // local row 0..31 (i,f,g,o x 8)
    const int gr = (r < 8) ? (j0 + r) : (r < 16) ? (HH + j0 + r - 8)
                 : (r < 24) ? (2 * HH + j0 + r - 16) : (3 * HH + j0 + r - 24);
    const int which = r >> 4, cc = r & 15;
    const float* src = W_hh + (size_t)gr * HH;
    const int k0 = (tid & 15) * 128;
    #pragma unroll
    for (int k8 = 0; k8 < 16; ++k8) {
      const int k = k0 + k8 * 8;
      bf16x8 v = cvt8(src + k);
      const int ent = ((k >> 5) * 2 + which) * 64 + ((k >> 3) & 3) * 16 + cc;
      *(bf16x8*)(Wlds + (size_t)ent * 8) = v;
    }
  }

  const int tb = tid >> 3, tj = tid & 7;
  const int jg = j0 + tj;
  const float bia = b_ih[jg] + b_hh[jg];
  const float bfa = b_ih[HH + jg] + b_hh[HH + jg];
  const float bga = b_ih[2 * HH + jg] + b_hh[2 * HH + jg];
  const float boa = b_ih[3 * HH + jg] + b_hh[3 * HH + jg];
  float cst = 0.f;

  const int arow = m * 16 + c;
  const int r0 = (c < 8) ? (j0 + c) : (HH + j0 + c - 8);          // i | f rows
  const int r1 = (c < 8) ? (2 * HH + j0 + c) : (3 * HH + j0 + c - 8); // g | o rows

  __syncthreads();

  for (int t = 0; t < TT; ++t) {
    const u16* hs = (t & 1) ? h1 : h0;
    u16* hd = (t & 1) ? h0 : h1;
    f32x4 acc0 = {0.f, 0.f, 0.f, 0.f};
    f32x4 acc1 = {0.f, 0.f, 0.f, 0.f};

    // ---- x-part (independent of h_{t-1}; hides barrier latency) ----
    #pragma unroll 4
    for (int i = 0; i < 16; ++i) {
      const int k = khalf * 512 + i * 32 + g * 8;
      bf16x8 a;
      if constexpr (XMODE == 1) a = *(const bf16x8*)(xbT + ((size_t)t * BB + arow) * DD + k);
      else                      a = cvt8(x + ((size_t)arow * TT + t) * DD + k);
      bf16x8 b0 = *(const bf16x8*)(wihb + (size_t)r0 * DD + k);
      bf16x8 b1 = *(const bf16x8*)(wihb + (size_t)r1 * DD + k);
      acc0 = __builtin_amdgcn_mfma_f32_16x16x32_bf16(a, b0, acc0, 0, 0, 0);
      acc1 = __builtin_amdgcn_mfma_f32_16x16x32_bf16(a, b1, acc1, 0, 0, 0);
    }

    // ---- wait: all WGs finished step t-1 (bounded spin; no atomic RMW) ----
    if (t > 0 && tid < 256) {
      int iters = 0;
      while (__hip_atomic_load(slots + tid, __ATOMIC_RELAXED, __HIP_MEMORY_SCOPE_AGENT) < t) {
        __builtin_amdgcn_s_sleep(1);
        if (++iters > (1 << 17)) break;   // fail loud (wrong answer), never hang
      }
    }
    __syncthreads();
    __threadfence();   // acquire: invalidate L1 before reading h_{t-1}

    // ---- h-part ----
    const u16* hrow = hs + (size_t)arow * HH;
    #pragma unroll 8
    for (int i = 0; i < 32; ++i) {
      const int kb = khalf * 32 + i;
      bf16x8 a = *(const bf16x8*)(hrow + (size_t)kb * 32 + g * 8);
      bf16x8 b0 = *(const bf16x8*)(Wlds + (size_t)((kb * 2 + 0) * 64 + lane) * 8);
      bf16x8 b1 = *(const bf16x8*)(Wlds + (size_t)((kb * 2 + 1) * 64 + lane) * 8);
      acc0 = __builtin_amdgcn_mfma_f32_16x16x32_bf16(a, b0, acc0, 0, 0, 0);
      acc1 = __builtin_amdgcn_mfma_f32_16x16x32_bf16(a, b1, acc1, 0, 0, 0);
    }

    // ---- reduce k-halves ----
    if (khalf == 1) {
      #pragma unroll
      for (int q = 0; q < 4; ++q) {
        red[((m * 2 + 0) * 64 + lane) * 4 + q] = acc0[q];
        red[((m * 2 + 1) * 64 + lane) * 4 + q] = acc1[q];
      }
    }
    __syncthreads();
    if (khalf == 0) {
      #pragma unroll
      for (int q = 0; q < 4; ++q) {
        const float s0 = acc0[q] + red[((m * 2 + 0) * 64 + lane) * 4 + q];
        const float s1 = acc1[q] + red[((m * 2 + 1) * 64 + lane) * 4 + q];
        const int b = m * 16 + g * 4 + q;
        gst[b * 36 + c] = s0;        // i (c<8) | f (c>=8)
        gst[b * 36 + 16 + c] = s1;   // g (c<8) | o (c>=8)
      }
    }
    __syncthreads();

    // ---- gates + state update (one (batch, j) pair per thread) ----
    {
      const float ip = gst[tb * 36 + tj]      + bia;
      const float fp = gst[tb * 36 + 8 + tj]  + bfa;
      const float gp = gst[tb * 36 + 16 + tj] + bga;
      const float op = gst[tb * 36 + 24 + tj] + boa;
      const float ig = 1.f / (1.f + expf(-ip));
      const float fg = 1.f / (1.f + expf(-fp));
      const float gv = tanhf(gp);
      const float og = 1.f / (1.f + expf(-op));
      cst = fg * cst + ig * gv;
      hd[(size_t)tb * HH + jg] = f2bf(og * tanhf(cst));
    }

    // ---- arrive: release h_t ----
    __threadfence();
    __syncthreads();
    if (tid == 0)
      __hip_atomic_store(slots + wg, t + 1, __ATOMIC_RELAXED, __HIP_MEMORY_SCOPE_AGENT);
  }
}

// ======================= fallback per-step kernel (round-1 proven, MODE 0) =======================
__global__ __launch_bounds__(512)
void lstm_step_kernel(const float* __restrict__ x,
                      const float* __restrict__ W_ih, const float* __restrict__ W_hh,
                      const float* __restrict__ b_ih, const float* __restrict__ b_hh,
                      const u16* __restrict__ h_src, u16* __restrict__ h_dst,
                      float* __restrict__ cbuf, int t) {
  const int tid = threadIdx.x;
  const int wave = tid >> 6, lane = tid & 63;
  const int m = wave & 3, khalf = wave >> 2;
  const int j0 = blockIdx.x * 8;
  const int c = lane & 15;
  const int arow = m * 16 + c;
  const int koff = (lane >> 4) * 8;
  const int r0 = (c < 8) ? (j0 + c) : (HH + j0 + c - 8);
  const int r1 = (c < 8) ? (2 * HH + j0 + c) : (3 * HH + j0 + c - 8);

  f32x4 acc0 = {0.f, 0.f, 0.f, 0.f};
  f32x4 acc1 = {0.f, 0.f, 0.f, 0.f};

  if (khalf == 0) {
    const size_t xrow = ((size_t)arow * TT + t) * DD;
    #pragma unroll 4
    for (int kb = 0; kb < 32; ++kb) {
      const int k = kb * 32 + koff;
      bf16x8 a = cvt8(x + xrow + k);
      bf16x8 b0 = cvt8(W_ih + (size_t)r0 * DD + k);
      bf16x8 b1 = cvt8(W_ih + (size_t)r1 * DD + k);
      acc0 = __builtin_amdgcn_mfma_f32_16x16x32_bf16(a, b0, acc0, 0, 0, 0);
      acc1 = __builtin_amdgcn_mfma_f32_16x16x32_bf16(a, b1, acc1, 0, 0, 0);
    }
    #pragma unroll 4
    for (int kb = 0; kb < 16; ++kb) {
      const int kh = kb * 32 + koff;
      bf16x8 a = *(const bf16x8*)(h_src + (size_t)arow * HH + kh);
      bf16x8 b0 = cvt8(W_hh + (size_t)r0 * HH + kh);
      bf16x8 b1 = cvt8(W_hh + (size_t)r1 * HH + kh);
      acc0 = __builtin_amdgcn_mfma_f32_16x16x32_bf16(a, b0, acc0, 0, 0, 0);
      acc1 = __builtin_amdgcn_mfma_f32_16x16x32_bf16(a, b1, acc1, 0, 0, 0);
    }
  } else {
    #pragma unroll 4
    for (int kb = 0; kb < 48; ++kb) {
      const int kh = 512 + kb * 32 + koff;
      bf16x8 a = *(const bf16x8*)(h_src + (size_t)arow * HH + kh);
      bf16x8 b0 = cvt8(W_hh + (size_t)r0 * HH + kh);
      bf16x8 b1 = cvt8(W_hh + (size_t)r1 * HH + kh);
      acc0 = __builtin_amdgcn_mfma_f32_16x16x32_bf16(a, b0, acc0, 0, 0, 0);
      acc1 = __builtin_amdgcn_mfma_f32_16x16x32_bf16(a, b1, acc1, 0, 0, 0);
    }
  }

  __shared__ float red[4][2][64][4];
  if (khalf == 1) {
    #pragma unroll
    for (int q = 0; q < 4; ++q) { red[m][0][lane][q] = acc0[q]; red[m][1][lane][q] = acc1[q]; }
  }
  __syncthreads();
  if (khalf == 1) return;
  #pragma unroll
  for (int q = 0; q < 4; ++q) { acc0[q] += red[m][0][lane][q]; acc1[q] += red[m][1][lane][q]; }

  const float bias0 = b_ih[r0] + b_hh[r0];
  const float bias1 = b_ih[r1] + b_hh[r1];
  #pragma unroll
  for (int q = 0; q < 4; ++q) { acc0[q] += bias0; acc1[q] += bias1; }

  float fpre[4], opre[4];
  #pragma unroll
  for (int q = 0; q < 4; ++q) {
    fpre[q] = __shfl_xor(acc0[q], 8);
    opre[q] = __shfl_xor(acc1[q], 8);
  }

  if (c < 8) {
    const int j = j0 + c;
    #pragma unroll
    for (int q = 0; q < 4; ++q) {
      const int b = m * 16 + (lane >> 4) * 4 + q;
      const float ig = 1.f / (1.f + expf(-acc0[q]));
      const float fg = 1.f / (1.f + expf(-fpre[q]));
      const float gg = tanhf(acc1[q]);
      const float og = 1.f / (1.f + expf(-opre[q]));
      const float cold = cbuf[(size_t)b * HH + j];
      const float cn = fg * cold + ig * gg;
      cbuf[(size_t)b * HH + j] = cn;
      h_dst[(size_t)b * HH + j] = f2bf(og * tanhf(cn));
    }
  }
}

// ======================= head =======================
__global__ __launch_bounds__(256)
void head_kernel(const u16* __restrict__ hfin, const float* __restrict__ W_head,
                 const float* __restrict__ b_head, float* __restrict__ out) {
  const int tid = threadIdx.x, wave = tid >> 6, lane = tid & 63;
  const int m = wave;
  const int c = lane & 15;
  const int koff = (lane >> 4) * 8;
  const int d = blockIdx.x * 16 + c;
  const int arow = m * 16 + c;
  f32x4 acc = {0.f, 0.f, 0.f, 0.f};
  #pragma unroll 4
  for (int kb = 0; kb < 64; ++kb) {
    const int k = kb * 32 + koff;
    bf16x8 a = *(const bf16x8*)(hfin + (size_t)arow * HH + k);
    bf16x8 b = cvt8(W_head + (size_t)d * HH + k);
    acc = __builtin_amdgcn_mfma_f32_16x16x32_bf16(a, b, acc, 0, 0, 0);
  }
  const float bh = b_head[d];
  #pragma unroll
  for (int q = 0; q < 4; ++q) {
    const int b = m * 16 + (lane >> 4) * 4 + q;
    out[(size_t)b * DD + d] = acc[q] + bh;
  }
}

extern "C" void kernel_launch(void* const* d_in, const int* in_sizes, int n_in,
                              void* d_out, int out_size, void* d_ws, size_t ws_size,
                              hipStream_t stream) {
  const float* x      = (const float*)d_in[0];
  const float* W_ih   = (const float*)d_in[1];
  const float* W_hh   = (const float*)d_in[2];
  const float* b_ih   = (const float*)d_in[3];
  const float* b_hh   = (const float*)d_in[4];
  const float* W_head = (const float*)d_in[5];
  const float* b_head = (const float*)d_in[6];
  float* out = (float*)d_out;

  char* ws = (char*)d_ws;
  u16*  h0    = (u16*)(ws + 0);                    // 256 KB
  u16*  h1    = (u16*)(ws + 256 * 1024);           // 256 KB
  int*  slots = (int*)(ws + 512 * 1024);           // 1 KB (persistent modes)
  float* cbuf = (float*)(ws + 512 * 1024);         // 512 KB (fallback mode only)
  u16*  wihb  = (u16*)(ws + (1ull << 20));         // 16 MB @ 1 MB
  u16*  xbT   = (u16*)(ws + (17ull << 20));        // 64 MB @ 17 MB

  const size_t NEED1 = (81ull << 20);
  const size_t NEED0 = (17ull << 20);

  hipMemsetAsync(ws, 0, 1u << 20, stream);   // zero h0/h1/slots/cbuf every launch

  if (ws_size >= NEED0) {
    {
      const int n8 = (int)((size_t)GG * DD / 8);
      conv_wih_kernel<<<(n8 + 255) / 256, 256, 0, stream>>>(W_ih, wihb);
    }
    if (ws_size >= NEED1) {
      const int n8 = (int)((size_t)BB * TT * DD / 8);
      conv_xT_kernel<<<(n8 + 255) / 256, 256, 0, stream>>>(x, xbT);
      lstm_persistent<1><<<256, 512, 0, stream>>>(x, xbT, wihb, W_hh, b_ih, b_hh, h0, h1, slots);
    } else {
      lstm_persistent<0><<<256, 512, 0, stream>>>(x, xbT, wihb, W_hh, b_ih, b_hh, h0, h1, slots);
    }
  } else {
    for (int t = 0; t < TT; ++t) {
      u16* hs = (t & 1) ? h1 : h0;
      u16* hd = (t & 1) ? h0 : h1;
      lstm_step_kernel<<<256, 512, 0, stream>>>(x, W_ih, W_hh, b_ih, b_hh, hs, hd, cbuf, t);
    }
  }

  // t=511 (odd) -> final h in h0
  head_kernel<<<64, 256, 0, stream>>>(h0, W_head, b_head, out);
}

// Round 4
// 15198.096 us; speedup vs baseline: 3.3724x; 3.3724x over previous
//
#include <hip/hip_runtime.h>
#include <hip/hip_bf16.h>
#include <cstdint>
#include <cstddef>

#define BB 64
#define TT 512
#define DD 1024
#define HH 2048
#define GG 8192   // 4*H

typedef unsigned short u16;
typedef __attribute__((ext_vector_type(8))) short bf16x8;
typedef __attribute__((ext_vector_type(4))) float f32x4;

__device__ __forceinline__ u16 f2bf(float f) {
  union { float f; uint32_t u; } v; v.f = f;
  uint32_t r = v.u + 0x7FFFu + ((v.u >> 16) & 1u);  // RNE
  return (u16)(r >> 16);
}
__device__ __forceinline__ float bf2f(u16 h) {
  union { uint32_t u; float f; } v; v.u = ((uint32_t)h) << 16; return v.f;
}

__device__ __forceinline__ bf16x8 cvt8(const float* __restrict__ p) {
  float4 a = *(const float4*)p;
  float4 b = *(const float4*)(p + 4);
  bf16x8 r;
  r[0] = (short)f2bf(a.x); r[1] = (short)f2bf(a.y);
  r[2] = (short)f2bf(a.z); r[3] = (short)f2bf(a.w);
  r[4] = (short)f2bf(b.x); r[5] = (short)f2bf(b.y);
  r[6] = (short)f2bf(b.z); r[7] = (short)f2bf(b.w);
  return r;
}

// ---- preps ----
__global__ void conv_wih_kernel(const float* __restrict__ W, u16* __restrict__ Wb) {
  size_t idx = (size_t)blockIdx.x * blockDim.x + threadIdx.x;
  if (idx >= (size_t)GG * DD / 8) return;
  *(bf16x8*)(Wb + idx * 8) = cvt8(W + idx * 8);
}

// x: [B][T][D] fp32 -> xbT: [T][B][D] bf16
__global__ void conv_xT_kernel(const float* __restrict__ x, u16* __restrict__ xbT) {
  size_t idx = (size_t)blockIdx.x * blockDim.x + threadIdx.x;
  if (idx >= (size_t)BB * TT * DD / 8) return;
  const int col8 = (int)(idx & 127);
  const int row = (int)(idx >> 7);          // b*512 + t
  const int b = row >> 9, t = row & 511;
  bf16x8 v = cvt8(x + (size_t)row * DD + col8 * 8);
  *(bf16x8*)(xbT + ((size_t)t * BB + b) * DD + col8 * 8) = v;
}

// ======================= persistent LSTM =======================
// 256 WGs x 512 thr, 1 WG/CU (forced by 145 KB LDS). WG owns h cols j0..j0+7
// (32 gate rows). W_hh slice LDS-stationary; W_ih slice L2-resident; c in regs.
// Grid barrier: hierarchical flags, 64B-padded. Arrive: 1 store/WG. WG0
// aggregates 256 slots and releases 256 private go-flags; each WG polls its
// OWN flag with 1 thread. Fences: executed by tid0 ONLY (one wbl2/inv per CU
// per step, not 512).
template<int XMODE>   // 1: x from xbT [T,B,D] bf16; 0: x fp32 [B,T,D] direct
__global__ __launch_bounds__(512, 1)
void lstm_persistent(const float* __restrict__ x, const u16* __restrict__ xbT,
                     const u16* __restrict__ wihb, const float* __restrict__ W_hh,
                     const float* __restrict__ b_ih, const float* __restrict__ b_hh,
                     u16* __restrict__ h0, u16* __restrict__ h1,
                     int* __restrict__ arrv, int* __restrict__ gof) {
  __shared__ u16 Wlds[64 * 2 * 64 * 8];   // 128 KB  [kb][which][lane][8]
  __shared__ float red[4 * 2 * 64 * 4];   // 8 KB
  __shared__ float gst[64 * 36];          // 9 KB (padded rows)

  const int tid = threadIdx.x;
  const int wave = tid >> 6, lane = tid & 63;
  const int m = wave & 3, khalf = wave >> 2;
  const int c = lane & 15, g = lane >> 4;
  const int wg = blockIdx.x, j0 = wg * 8;

  // ---- one-time: W_hh slice -> LDS in MFMA fragment order ----
  {
    const int r = tid >> 4;              // local row 0..31 (i,f,g,o x 8)
    const int gr = (r < 8) ? (j0 + r) : (r < 16) ? (HH + j0 + r - 8)
                 : (r < 24) ? (2 * HH + j0 + r - 16) : (3 * HH + j0 + r - 24);
    const int which = r >> 4, cc = r & 15;
    const float* src = W_hh + (size_t)gr * HH;
    const int k0 = (tid & 15) * 128;
    #pragma unroll
    for (int k8 = 0; k8 < 16; ++k8) {
      const int k = k0 + k8 * 8;
      bf16x8 v = cvt8(src + k);
      const int ent = ((k >> 5) * 2 + which) * 64 + ((k >> 3) & 3) * 16 + cc;
      *(bf16x8*)(Wlds + (size_t)ent * 8) = v;
    }
  }

  const int tb = tid >> 3, tj = tid & 7;
  const int jg = j0 + tj;
  const float bia = b_ih[jg] + b_hh[jg];
  const float bfa = b_ih[HH + jg] + b_hh[HH + jg];
  const float bga = b_ih[2 * HH + jg] + b_hh[2 * HH + jg];
  const float boa = b_ih[3 * HH + jg] + b_hh[3 * HH + jg];
  float cst = 0.f;

  const int arow = m * 16 + c;
  const int r0 = (c < 8) ? (j0 + c) : (HH + j0 + c - 8);          // i | f rows
  const int r1 = (c < 8) ? (2 * HH + j0 + c) : (3 * HH + j0 + c - 8); // g | o rows

  __syncthreads();

  for (int t = 0; t < TT; ++t) {
    const u16* hs = (t & 1) ? h1 : h0;
    u16* hd = (t & 1) ? h0 : h1;
    f32x4 acc0 = {0.f, 0.f, 0.f, 0.f};
    f32x4 acc1 = {0.f, 0.f, 0.f, 0.f};

    // ---- x-part (independent of h_{t-1}; hides barrier latency) ----
    #pragma unroll 4
    for (int i = 0; i < 16; ++i) {
      const int k = khalf * 512 + i * 32 + g * 8;
      bf16x8 a;
      if constexpr (XMODE == 1) a = *(const bf16x8*)(xbT + ((size_t)t * BB + arow) * DD + k);
      else                      a = cvt8(x + ((size_t)arow * TT + t) * DD + k);
      bf16x8 b0 = *(const bf16x8*)(wihb + (size_t)r0 * DD + k);
      bf16x8 b1 = *(const bf16x8*)(wihb + (size_t)r1 * DD + k);
      acc0 = __builtin_amdgcn_mfma_f32_16x16x32_bf16(a, b0, acc0, 0, 0, 0);
      acc1 = __builtin_amdgcn_mfma_f32_16x16x32_bf16(a, b1, acc1, 0, 0, 0);
    }

    // ---- wait: all WGs finished step t-1 (hierarchical, low-contention) ----
    if (t > 0) {
      if (wg == 0) {
        if (tid < 256) {
          int iters = 0;
          while (__hip_atomic_load(arrv + tid * 16, __ATOMIC_RELAXED, __HIP_MEMORY_SCOPE_AGENT) < t) {
            __builtin_amdgcn_s_sleep(1);
            if (++iters > (1 << 17)) break;   // fail loud, never hang
          }
        }
        __syncthreads();
        if (tid < 256)
          __hip_atomic_store(gof + tid * 16, t, __ATOMIC_RELAXED, __HIP_MEMORY_SCOPE_AGENT);
      } else {
        if (tid == 0) {
          int iters = 0;
          while (__hip_atomic_load(gof + wg * 16, __ATOMIC_RELAXED, __HIP_MEMORY_SCOPE_AGENT) < t) {
            __builtin_amdgcn_s_sleep(1);
            if (++iters > (1 << 17)) break;
          }
        }
      }
      if (tid == 0) __threadfence();   // acquire (1 inv per CU, not 512)
    }
    __syncthreads();

    // ---- h-part ----
    const u16* hrow = hs + (size_t)arow * HH;
    #pragma unroll 8
    for (int i = 0; i < 32; ++i) {
      const int kb = khalf * 32 + i;
      bf16x8 a = *(const bf16x8*)(hrow + (size_t)kb * 32 + g * 8);
      bf16x8 b0 = *(const bf16x8*)(Wlds + (size_t)((kb * 2 + 0) * 64 + lane) * 8);
      bf16x8 b1 = *(const bf16x8*)(Wlds + (size_t)((kb * 2 + 1) * 64 + lane) * 8);
      acc0 = __builtin_amdgcn_mfma_f32_16x16x32_bf16(a, b0, acc0, 0, 0, 0);
      acc1 = __builtin_amdgcn_mfma_f32_16x16x32_bf16(a, b1, acc1, 0, 0, 0);
    }

    // ---- reduce k-halves ----
    if (khalf == 1) {
      #pragma unroll
      for (int q = 0; q < 4; ++q) {
        red[((m * 2 + 0) * 64 + lane) * 4 + q] = acc0[q];
        red[((m * 2 + 1) * 64 + lane) * 4 + q] = acc1[q];
      }
    }
    __syncthreads();
    if (khalf == 0) {
      #pragma unroll
      for (int q = 0; q < 4; ++q) {
        const float s0 = acc0[q] + red[((m * 2 + 0) * 64 + lane) * 4 + q];
        const float s1 = acc1[q] + red[((m * 2 + 1) * 64 + lane) * 4 + q];
        const int b = m * 16 + g * 4 + q;
        gst[b * 36 + c] = s0;        // i (c<8) | f (c>=8)
        gst[b * 36 + 16 + c] = s1;   // g (c<8) | o (c>=8)
      }
    }
    __syncthreads();

    // ---- gates + state update (one (batch, j) pair per thread) ----
    {
      const float ip = gst[tb * 36 + tj]      + bia;
      const float fp = gst[tb * 36 + 8 + tj]  + bfa;
      const float gp = gst[tb * 36 + 16 + tj] + bga;
      const float op = gst[tb * 36 + 24 + tj] + boa;
      const float ig = 1.f / (1.f + expf(-ip));
      const float fg = 1.f / (1.f + expf(-fp));
      const float gv = tanhf(gp);
      const float og = 1.f / (1.f + expf(-op));
      cst = fg * cst + ig * gv;
      hd[(size_t)tb * HH + jg] = f2bf(og * tanhf(cst));
    }

    // ---- arrive: release h_t (1 fence + 1 store per WG) ----
    __syncthreads();                 // drains each thread's vmcnt -> h in L2
    if (tid == 0) {
      __threadfence();               // writeback dirty L2 lines (1 wbl2 per CU)
      __hip_atomic_store(arrv + wg * 16, t + 1, __ATOMIC_RELAXED, __HIP_MEMORY_SCOPE_AGENT);
    }
  }
}

// ======================= fallback per-step kernel (round-1 proven) =======================
__global__ __launch_bounds__(512)
void lstm_step_kernel(const float* __restrict__ x,
                      const float* __restrict__ W_ih, const float* __restrict__ W_hh,
                      const float* __restrict__ b_ih, const float* __restrict__ b_hh,
                      const u16* __restrict__ h_src, u16* __restrict__ h_dst,
                      float* __restrict__ cbuf, int t) {
  const int tid = threadIdx.x;
  const int wave = tid >> 6, lane = tid & 63;
  const int m = wave & 3, khalf = wave >> 2;
  const int j0 = blockIdx.x * 8;
  const int c = lane & 15;
  const int arow = m * 16 + c;
  const int koff = (lane >> 4) * 8;
  const int r0 = (c < 8) ? (j0 + c) : (HH + j0 + c - 8);
  const int r1 = (c < 8) ? (2 * HH + j0 + c) : (3 * HH + j0 + c - 8);

  f32x4 acc0 = {0.f, 0.f, 0.f, 0.f};
  f32x4 acc1 = {0.f, 0.f, 0.f, 0.f};

  if (khalf == 0) {
    const size_t xrow = ((size_t)arow * TT + t) * DD;
    #pragma unroll 4
    for (int kb = 0; kb < 32; ++kb) {
      const int k = kb * 32 + koff;
      bf16x8 a = cvt8(x + xrow + k);
      bf16x8 b0 = cvt8(W_ih + (size_t)r0 * DD + k);
      bf16x8 b1 = cvt8(W_ih + (size_t)r1 * DD + k);
      acc0 = __builtin_amdgcn_mfma_f32_16x16x32_bf16(a, b0, acc0, 0, 0, 0);
      acc1 = __builtin_amdgcn_mfma_f32_16x16x32_bf16(a, b1, acc1, 0, 0, 0);
    }
    #pragma unroll 4
    for (int kb = 0; kb < 16; ++kb) {
      const int kh = kb * 32 + koff;
      bf16x8 a = *(const bf16x8*)(h_src + (size_t)arow * HH + kh);
      bf16x8 b0 = cvt8(W_hh + (size_t)r0 * HH + kh);
      bf16x8 b1 = cvt8(W_hh + (size_t)r1 * HH + kh);
      acc0 = __builtin_amdgcn_mfma_f32_16x16x32_bf16(a, b0, acc0, 0, 0, 0);
      acc1 = __builtin_amdgcn_mfma_f32_16x16x32_bf16(a, b1, acc1, 0, 0, 0);
    }
  } else {
    #pragma unroll 4
    for (int kb = 0; kb < 48; ++kb) {
      const int kh = 512 + kb * 32 + koff;
      bf16x8 a = *(const bf16x8*)(h_src + (size_t)arow * HH + kh);
      bf16x8 b0 = cvt8(W_hh + (size_t)r0 * HH + kh);
      bf16x8 b1 = cvt8(W_hh + (size_t)r1 * HH + kh);
      acc0 = __builtin_amdgcn_mfma_f32_16x16x32_bf16(a, b0, acc0, 0, 0, 0);
      acc1 = __builtin_amdgcn_mfma_f32_16x16x32_bf16(a, b1, acc1, 0, 0, 0);
    }
  }

  __shared__ float red[4][2][64][4];
  if (khalf == 1) {
    #pragma unroll
    for (int q = 0; q < 4; ++q) { red[m][0][lane][q] = acc0[q]; red[m][1][lane][q] = acc1[q]; }
  }
  __syncthreads();
  if (khalf == 1) return;
  #pragma unroll
  for (int q = 0; q < 4; ++q) { acc0[q] += red[m][0][lane][q]; acc1[q] += red[m][1][lane][q]; }

  const float bias0 = b_ih[r0] + b_hh[r0];
  const float bias1 = b_ih[r1] + b_hh[r1];
  #pragma unroll
  for (int q = 0; q < 4; ++q) { acc0[q] += bias0; acc1[q] += bias1; }

  float fpre[4], opre[4];
  #pragma unroll
  for (int q = 0; q < 4; ++q) {
    fpre[q] = __shfl_xor(acc0[q], 8);
    opre[q] = __shfl_xor(acc1[q], 8);
  }

  if (c < 8) {
    const int j = j0 + c;
    #pragma unroll
    for (int q = 0; q < 4; ++q) {
      const int b = m * 16 + (lane >> 4) * 4 + q;
      const float ig = 1.f / (1.f + expf(-acc0[q]));
      const float fg = 1.f / (1.f + expf(-fpre[q]));
      const float gg = tanhf(acc1[q]);
      const float og = 1.f / (1.f + expf(-opre[q]));
      const float cold = cbuf[(size_t)b * HH + j];
      const float cn = fg * cold + ig * gg;
      cbuf[(size_t)b * HH + j] = cn;
      h_dst[(size_t)b * HH + j] = f2bf(og * tanhf(cn));
    }
  }
}

// ======================= head =======================
__global__ __launch_bounds__(256)
void head_kernel(const u16* __restrict__ hfin, const float* __restrict__ W_head,
                 const float* __restrict__ b_head, float* __restrict__ out) {
  const int tid = threadIdx.x, wave = tid >> 6, lane = tid & 63;
  const int m = wave;
  const int c = lane & 15;
  const int koff = (lane >> 4) * 8;
  const int d = blockIdx.x * 16 + c;
  const int arow = m * 16 + c;
  f32x4 acc = {0.f, 0.f, 0.f, 0.f};
  #pragma unroll 4
  for (int kb = 0; kb < 64; ++kb) {
    const int k = kb * 32 + koff;
    bf16x8 a = *(const bf16x8*)(hfin + (size_t)arow * HH + k);
    bf16x8 b = cvt8(W_head + (size_t)d * HH + k);
    acc = __builtin_amdgcn_mfma_f32_16x16x32_bf16(a, b, acc, 0, 0, 0);
  }
  const float bh = b_head[d];
  #pragma unroll
  for (int q = 0; q < 4; ++q) {
    const int b = m * 16 + (lane >> 4) * 4 + q;
    out[(size_t)b * DD + d] = acc[q] + bh;
  }
}

extern "C" void kernel_launch(void* const* d_in, const int* in_sizes, int n_in,
                              void* d_out, int out_size, void* d_ws, size_t ws_size,
                              hipStream_t stream) {
  const float* x      = (const float*)d_in[0];
  const float* W_ih   = (const float*)d_in[1];
  const float* W_hh   = (const float*)d_in[2];
  const float* b_ih   = (const float*)d_in[3];
  const float* b_hh   = (const float*)d_in[4];
  const float* W_head = (const float*)d_in[5];
  const float* b_head = (const float*)d_in[6];
  float* out = (float*)d_out;

  char* ws = (char*)d_ws;
  u16*  h0    = (u16*)(ws + 0);                    // 256 KB
  u16*  h1    = (u16*)(ws + 256 * 1024);           // 256 KB
  int*  arrv  = (int*)(ws + 512 * 1024);           // 16 KB padded flags
  int*  gof   = (int*)(ws + 544 * 1024);           // 16 KB padded flags
  float* cbuf = (float*)(ws + 512 * 1024);         // 512 KB (fallback mode only)
  u16*  wihb  = (u16*)(ws + (1ull << 20));         // 16 MB @ 1 MB
  u16*  xbT   = (u16*)(ws + (17ull << 20));        // 64 MB @ 17 MB

  const size_t NEED1 = (81ull << 20);
  const size_t NEED0 = (17ull << 20);

  hipMemsetAsync(ws, 0, 1u << 20, stream);   // zero h0/h1/flags/cbuf every launch

  if (ws_size >= NEED0) {
    {
      const int n8 = (int)((size_t)GG * DD / 8);
      conv_wih_kernel<<<(n8 + 255) / 256, 256, 0, stream>>>(W_ih, wihb);
    }
    if (ws_size >= NEED1) {
      const int n8 = (int)((size_t)BB * TT * DD / 8);
      conv_xT_kernel<<<(n8 + 255) / 256, 256, 0, stream>>>(x, xbT);
      lstm_persistent<1><<<256, 512, 0, stream>>>(x, xbT, wihb, W_hh, b_ih, b_hh, h0, h1, arrv, gof);
    } else {
      lstm_persistent<0><<<256, 512, 0, stream>>>(x, xbT, wihb, W_hh, b_ih, b_hh, h0, h1, arrv, gof);
    }
  } else {
    for (int t = 0; t < TT; ++t) {
      u16* hs = (t & 1) ? h1 : h0;
      u16* hd = (t & 1) ? h0 : h1;
      lstm_step_kernel<<<256, 512, 0, stream>>>(x, W_ih, W_hh, b_ih, b_hh, hs, hd, cbuf, t);
    }
  }

  // t=511 (odd) -> final h in h0
  head_kernel<<<64, 256, 0, stream>>>(h0, W_head, b_head, out);
}

// Round 5
// 10463.985 us; speedup vs baseline: 4.8982x; 1.4524x over previous
//
#include <hip/hip_runtime.h>
#include <hip/hip_bf16.h>
#include <cstdint>
#include <cstddef>

#define BB 64
#define TT 512
#define DD 1024
#define HH 2048
#define GG 8192   // 4*H

typedef unsigned short u16;
typedef __attribute__((ext_vector_type(8))) short bf16x8;
typedef __attribute__((ext_vector_type(4))) float f32x4;

__device__ __forceinline__ u16 f2bf(float f) {
  union { float f; uint32_t u; } v; v.f = f;
  uint32_t r = v.u + 0x7FFFu + ((v.u >> 16) & 1u);  // RNE
  return (u16)(r >> 16);
}
__device__ __forceinline__ float bf2f(u16 h) {
  union { uint32_t u; float f; } v; v.u = ((uint32_t)h) << 16; return v.f;
}

__device__ __forceinline__ bf16x8 cvt8(const float* __restrict__ p) {
  float4 a = *(const float4*)p;
  float4 b = *(const float4*)(p + 4);
  bf16x8 r;
  r[0] = (short)f2bf(a.x); r[1] = (short)f2bf(a.y);
  r[2] = (short)f2bf(a.z); r[3] = (short)f2bf(a.w);
  r[4] = (short)f2bf(b.x); r[5] = (short)f2bf(b.y);
  r[6] = (short)f2bf(b.z); r[7] = (short)f2bf(b.w);
  return r;
}

// coherent (agent-scope, L1+L2-bypass) 16B load/store — served at the
// coherence point (L3). Mirrors LLVM's gfx950 agent-relaxed-atomic lowering;
// no buffer_wbl2/buffer_inv needed anywhere.
__device__ __forceinline__ bf16x8 cohload16(const u16* p) {
  bf16x8 v;
  asm volatile("global_load_dwordx4 %0, %1, off sc0 sc1" : "=v"(v) : "v"(p));
  return v;
}
__device__ __forceinline__ void cohstore16(u16* p, bf16x8 v) {
  asm volatile("global_store_dwordx4 %0, %1, off sc0 sc1" :: "v"(p), "v"(v) : "memory");
}

// ---- preps ----
__global__ void conv_wih_kernel(const float* __restrict__ W, u16* __restrict__ Wb) {
  size_t idx = (size_t)blockIdx.x * blockDim.x + threadIdx.x;
  if (idx >= (size_t)GG * DD / 8) return;
  *(bf16x8*)(Wb + idx * 8) = cvt8(W + idx * 8);
}

// x: [B][T][D] fp32 -> xbT: [T][B][D] bf16
__global__ void conv_xT_kernel(const float* __restrict__ x, u16* __restrict__ xbT) {
  size_t idx = (size_t)blockIdx.x * blockDim.x + threadIdx.x;
  if (idx >= (size_t)BB * TT * DD / 8) return;
  const int col8 = (int)(idx & 127);
  const int row = (int)(idx >> 7);          // b*512 + t
  const int b = row >> 9, t = row & 511;
  bf16x8 v = cvt8(x + (size_t)row * DD + col8 * 8);
  *(bf16x8*)(xbT + ((size_t)t * BB + b) * DD + col8 * 8) = v;
}

// ======================= persistent LSTM =======================
// 256 WGs x 512 thr, 1 WG/CU (forced by 146 KB LDS). WG owns h cols j0..j0+7
// (32 gate rows). W_hh slice LDS-stationary; W_ih/x_t L2-cached (read-only).
// h crosses XCDs via sc0+sc1 write-through stores / bypass loads (L3-coherent)
// => NO threadfence (no 4MB L2 walks) in the steady-state loop.
template<int XMODE>   // 1: x from xbT [T,B,D] bf16; 0: x fp32 [B,T,D] direct
__global__ __launch_bounds__(512, 1)
void lstm_persistent(const float* __restrict__ x, const u16* __restrict__ xbT,
                     const u16* __restrict__ wihb, const float* __restrict__ W_hh,
                     const float* __restrict__ b_ih, const float* __restrict__ b_hh,
                     u16* __restrict__ h0, u16* __restrict__ h1,
                     int* __restrict__ arrv, int* __restrict__ gof) {
  __shared__ u16 Wlds[64 * 2 * 64 * 8];   // 128 KB  [kb][which][lane][8]
  __shared__ float red[4 * 2 * 64 * 4];   // 8 KB
  __shared__ float gst[64 * 36];          // 9 KB (padded rows)
  __shared__ u16 hsh[512];                // 1 KB staging for coherent h store

  const int tid = threadIdx.x;
  const int wave = tid >> 6, lane = tid & 63;
  const int m = wave & 3, khalf = wave >> 2;
  const int c = lane & 15, g = lane >> 4;
  const int wg = blockIdx.x, j0 = wg * 8;

  // ---- one-time: W_hh slice -> LDS in MFMA fragment order ----
  {
    const int r = tid >> 4;              // local row 0..31 (i,f,g,o x 8)
    const int gr = (r < 8) ? (j0 + r) : (r < 16) ? (HH + j0 + r - 8)
                 : (r < 24) ? (2 * HH + j0 + r - 16) : (3 * HH + j0 + r - 24);
    const int which = r >> 4, cc = r & 15;
    const float* src = W_hh + (size_t)gr * HH;
    const int k0 = (tid & 15) * 128;
    #pragma unroll
    for (int k8 = 0; k8 < 16; ++k8) {
      const int k = k0 + k8 * 8;
      bf16x8 v = cvt8(src + k);
      const int ent = ((k >> 5) * 2 + which) * 64 + ((k >> 3) & 3) * 16 + cc;
      *(bf16x8*)(Wlds + (size_t)ent * 8) = v;
    }
  }

  const int tb = tid >> 3, tj = tid & 7;
  const int jg = j0 + tj;
  const float bia = b_ih[jg] + b_hh[jg];
  const float bfa = b_ih[HH + jg] + b_hh[HH + jg];
  const float bga = b_ih[2 * HH + jg] + b_hh[2 * HH + jg];
  const float boa = b_ih[3 * HH + jg] + b_hh[3 * HH + jg];
  float cst = 0.f;

  const int arow = m * 16 + c;
  const int r0 = (c < 8) ? (j0 + c) : (HH + j0 + c - 8);          // i | f rows
  const int r1 = (c < 8) ? (2 * HH + j0 + c) : (3 * HH + j0 + c - 8); // g | o rows

  __syncthreads();

  for (int t = 0; t < TT; ++t) {
    const u16* hs = (t & 1) ? h1 : h0;
    u16* hd = (t & 1) ? h0 : h1;
    f32x4 acc0 = {0.f, 0.f, 0.f, 0.f};
    f32x4 acc1 = {0.f, 0.f, 0.f, 0.f};

    // ---- x-part (independent of h_{t-1}; overlaps barrier propagation) ----
    #pragma unroll 4
    for (int i = 0; i < 16; ++i) {
      const int k = khalf * 512 + i * 32 + g * 8;
      bf16x8 a;
      if constexpr (XMODE == 1) a = *(const bf16x8*)(xbT + ((size_t)t * BB + arow) * DD + k);
      else                      a = cvt8(x + ((size_t)arow * TT + t) * DD + k);
      bf16x8 b0 = *(const bf16x8*)(wihb + (size_t)r0 * DD + k);
      bf16x8 b1 = *(const bf16x8*)(wihb + (size_t)r1 * DD + k);
      acc0 = __builtin_amdgcn_mfma_f32_16x16x32_bf16(a, b0, acc0, 0, 0, 0);
      acc1 = __builtin_amdgcn_mfma_f32_16x16x32_bf16(a, b1, acc1, 0, 0, 0);
    }

    // ---- wait: all WGs finished step t-1 (hierarchical flags, no fences) ----
    if (t > 0) {
      if (wg == 0) {
        if (tid < 256) {
          int iters = 0;
          while (__hip_atomic_load(arrv + tid * 16, __ATOMIC_RELAXED, __HIP_MEMORY_SCOPE_AGENT) < t) {
            __builtin_amdgcn_s_sleep(1);
            if (++iters > (1 << 17)) break;   // fail loud, never hang
          }
        }
        __syncthreads();
        if (tid < 256)
          __hip_atomic_store(gof + tid * 16, t, __ATOMIC_RELAXED, __HIP_MEMORY_SCOPE_AGENT);
      } else {
        if (tid == 0) {
          int iters = 0;
          while (__hip_atomic_load(gof + wg * 16, __ATOMIC_RELAXED, __HIP_MEMORY_SCOPE_AGENT) < t) {
            __builtin_amdgcn_s_sleep(1);
            if (++iters > (1 << 17)) break;
          }
        }
      }
    }
    __syncthreads();

    // ---- h-part: coherent 32x16B burst into registers, staged consume ----
    {
      bf16x8 hf[32];
      const u16* hrow = hs + (size_t)arow * HH + g * 8;
      #pragma unroll
      for (int i = 0; i < 32; ++i)
        hf[i] = cohload16(hrow + (size_t)(khalf * 32 + i) * 32);

      #pragma unroll
      for (int grp = 0; grp < 4; ++grp) {
        if (grp == 0)      asm volatile("s_waitcnt vmcnt(24)" ::: "memory");
        else if (grp == 1) asm volatile("s_waitcnt vmcnt(16)" ::: "memory");
        else if (grp == 2) asm volatile("s_waitcnt vmcnt(8)"  ::: "memory");
        else               asm volatile("s_waitcnt vmcnt(0)"  ::: "memory");
        __builtin_amdgcn_sched_barrier(0);
        #pragma unroll
        for (int i2 = 0; i2 < 8; ++i2) {
          const int i = grp * 8 + i2;
          const int kb = khalf * 32 + i;
          bf16x8 b0 = *(const bf16x8*)(Wlds + (size_t)((kb * 2 + 0) * 64 + lane) * 8);
          bf16x8 b1 = *(const bf16x8*)(Wlds + (size_t)((kb * 2 + 1) * 64 + lane) * 8);
          acc0 = __builtin_amdgcn_mfma_f32_16x16x32_bf16(hf[i], b0, acc0, 0, 0, 0);
          acc1 = __builtin_amdgcn_mfma_f32_16x16x32_bf16(hf[i], b1, acc1, 0, 0, 0);
        }
      }
    }

    // ---- reduce k-halves ----
    if (khalf == 1) {
      #pragma unroll
      for (int q = 0; q < 4; ++q) {
        red[((m * 2 + 0) * 64 + lane) * 4 + q] = acc0[q];
        red[((m * 2 + 1) * 64 + lane) * 4 + q] = acc1[q];
      }
    }
    __syncthreads();
    if (khalf == 0) {
      #pragma unroll
      for (int q = 0; q < 4; ++q) {
        const float s0 = acc0[q] + red[((m * 2 + 0) * 64 + lane) * 4 + q];
        const float s1 = acc1[q] + red[((m * 2 + 1) * 64 + lane) * 4 + q];
        const int b = m * 16 + g * 4 + q;
        gst[b * 36 + c] = s0;        // i (c<8) | f (c>=8)
        gst[b * 36 + 16 + c] = s1;   // g (c<8) | o (c>=8)
      }
    }
    __syncthreads();

    // ---- gates + state update (one (batch, j) pair per thread) ----
    {
      const float ip = gst[tb * 36 + tj]      + bia;
      const float fp = gst[tb * 36 + 8 + tj]  + bfa;
      const float gp = gst[tb * 36 + 16 + tj] + bga;
      const float op = gst[tb * 36 + 24 + tj] + boa;
      const float ig = 1.f / (1.f + expf(-ip));
      const float fg = 1.f / (1.f + expf(-fp));
      const float gv = tanhf(gp);
      const float og = 1.f / (1.f + expf(-op));
      cst = fg * cst + ig * gv;
      hsh[tb * 8 + tj] = f2bf(og * tanhf(cst));
    }
    __syncthreads();

    // ---- coherent h store (64 threads x 16B) + arrive ----
    if (tid < 64) {
      bf16x8 v = *(const bf16x8*)(hsh + tid * 8);
      cohstore16(hd + (size_t)tid * HH + j0, v);
      asm volatile("s_waitcnt vmcnt(0)" ::: "memory");   // data at coherence point
    }
    __syncthreads();
    if (tid == 0)
      __hip_atomic_store(arrv + wg * 16, t + 1, __ATOMIC_RELAXED, __HIP_MEMORY_SCOPE_AGENT);
  }
}

// ======================= fallback per-step kernel (round-1 proven) =======================
__global__ __launch_bounds__(512)
void lstm_step_kernel(const float* __restrict__ x,
                      const float* __restrict__ W_ih, const float* __restrict__ W_hh,
                      const float* __restrict__ b_ih, const float* __restrict__ b_hh,
                      const u16* __restrict__ h_src, u16* __restrict__ h_dst,
                      float* __restrict__ cbuf, int t) {
  const int tid = threadIdx.x;
  const int wave = tid >> 6, lane = tid & 63;
  const int m = wave & 3, khalf = wave >> 2;
  const int j0 = blockIdx.x * 8;
  const int c = lane & 15;
  const int arow = m * 16 + c;
  const int koff = (lane >> 4) * 8;
  const int r0 = (c < 8) ? (j0 + c) : (HH + j0 + c - 8);
  const int r1 = (c < 8) ? (2 * HH + j0 + c) : (3 * HH + j0 + c - 8);

  f32x4 acc0 = {0.f, 0.f, 0.f, 0.f};
  f32x4 acc1 = {0.f, 0.f, 0.f, 0.f};

  if (khalf == 0) {
    const size_t xrow = ((size_t)arow * TT + t) * DD;
    #pragma unroll 4
    for (int kb = 0; kb < 32; ++kb) {
      const int k = kb * 32 + koff;
      bf16x8 a = cvt8(x + xrow + k);
      bf16x8 b0 = cvt8(W_ih + (size_t)r0 * DD + k);
      bf16x8 b1 = cvt8(W_ih + (size_t)r1 * DD + k);
      acc0 = __builtin_amdgcn_mfma_f32_16x16x32_bf16(a, b0, acc0, 0, 0, 0);
      acc1 = __builtin_amdgcn_mfma_f32_16x16x32_bf16(a, b1, acc1, 0, 0, 0);
    }
    #pragma unroll 4
    for (int kb = 0; kb < 16; ++kb) {
      const int kh = kb * 32 + koff;
      bf16x8 a = *(const bf16x8*)(h_src + (size_t)arow * HH + kh);
      bf16x8 b0 = cvt8(W_hh + (size_t)r0 * HH + kh);
      bf16x8 b1 = cvt8(W_hh + (size_t)r1 * HH + kh);
      acc0 = __builtin_amdgcn_mfma_f32_16x16x32_bf16(a, b0, acc0, 0, 0, 0);
      acc1 = __builtin_amdgcn_mfma_f32_16x16x32_bf16(a, b1, acc1, 0, 0, 0);
    }
  } else {
    #pragma unroll 4
    for (int kb = 0; kb < 48; ++kb) {
      const int kh = 512 + kb * 32 + koff;
      bf16x8 a = *(const bf16x8*)(h_src + (size_t)arow * HH + kh);
      bf16x8 b0 = cvt8(W_hh + (size_t)r0 * HH + kh);
      bf16x8 b1 = cvt8(W_hh + (size_t)r1 * HH + kh);
      acc0 = __builtin_amdgcn_mfma_f32_16x16x32_bf16(a, b0, acc0, 0, 0, 0);
      acc1 = __builtin_amdgcn_mfma_f32_16x16x32_bf16(a, b1, acc1, 0, 0, 0);
    }
  }

  __shared__ float red[4][2][64][4];
  if (khalf == 1) {
    #pragma unroll
    for (int q = 0; q < 4; ++q) { red[m][0][lane][q] = acc0[q]; red[m][1][lane][q] = acc1[q]; }
  }
  __syncthreads();
  if (khalf == 1) return;
  #pragma unroll
  for (int q = 0; q < 4; ++q) { acc0[q] += red[m][0][lane][q]; acc1[q] += red[m][1][lane][q]; }

  const float bias0 = b_ih[r0] + b_hh[r0];
  const float bias1 = b_ih[r1] + b_hh[r1];
  #pragma unroll
  for (int q = 0; q < 4; ++q) { acc0[q] += bias0; acc1[q] += bias1; }

  float fpre[4], opre[4];
  #pragma unroll
  for (int q = 0; q < 4; ++q) {
    fpre[q] = __shfl_xor(acc0[q], 8);
    opre[q] = __shfl_xor(acc1[q], 8);
  }

  if (c < 8) {
    const int j = j0 + c;
    #pragma unroll
    for (int q = 0; q < 4; ++q) {
      const int b = m * 16 + (lane >> 4) * 4 + q;
      const float ig = 1.f / (1.f + expf(-acc0[q]));
      const float fg = 1.f / (1.f + expf(-fpre[q]));
      const float gg = tanhf(acc1[q]);
      const float og = 1.f / (1.f + expf(-opre[q]));
      const float cold = cbuf[(size_t)b * HH + j];
      const float cn = fg * cold + ig * gg;
      cbuf[(size_t)b * HH + j] = cn;
      h_dst[(size_t)b * HH + j] = f2bf(og * tanhf(cn));
    }
  }
}

// ======================= head =======================
__global__ __launch_bounds__(256)
void head_kernel(const u16* __restrict__ hfin, const float* __restrict__ W_head,
                 const float* __restrict__ b_head, float* __restrict__ out) {
  const int tid = threadIdx.x, wave = tid >> 6, lane = tid & 63;
  const int m = wave;
  const int c = lane & 15;
  const int koff = (lane >> 4) * 8;
  const int d = blockIdx.x * 16 + c;
  const int arow = m * 16 + c;
  f32x4 acc = {0.f, 0.f, 0.f, 0.f};
  #pragma unroll 4
  for (int kb = 0; kb < 64; ++kb) {
    const int k = kb * 32 + koff;
    bf16x8 a = *(const bf16x8*)(hfin + (size_t)arow * HH + k);
    bf16x8 b = cvt8(W_head + (size_t)d * HH + k);
    acc = __builtin_amdgcn_mfma_f32_16x16x32_bf16(a, b, acc, 0, 0, 0);
  }
  const float bh = b_head[d];
  #pragma unroll
  for (int q = 0; q < 4; ++q) {
    const int b = m * 16 + (lane >> 4) * 4 + q;
    out[(size_t)b * DD + d] = acc[q] + bh;
  }
}

extern "C" void kernel_launch(void* const* d_in, const int* in_sizes, int n_in,
                              void* d_out, int out_size, void* d_ws, size_t ws_size,
                              hipStream_t stream) {
  const float* x      = (const float*)d_in[0];
  const float* W_ih   = (const float*)d_in[1];
  const float* W_hh   = (const float*)d_in[2];
  const float* b_ih   = (const float*)d_in[3];
  const float* b_hh   = (const float*)d_in[4];
  const float* W_head = (const float*)d_in[5];
  const float* b_head = (const float*)d_in[6];
  float* out = (float*)d_out;

  char* ws = (char*)d_ws;
  u16*  h0    = (u16*)(ws + 0);                    // 256 KB
  u16*  h1    = (u16*)(ws + 256 * 1024);           // 256 KB
  int*  arrv  = (int*)(ws + 512 * 1024);           // 16 KB padded flags
  int*  gof   = (int*)(ws + 544 * 1024);           // 16 KB padded flags
  float* cbuf = (float*)(ws + 512 * 1024);         // 512 KB (fallback mode only)
  u16*  wihb  = (u16*)(ws + (1ull << 20));         // 16 MB @ 1 MB
  u16*  xbT   = (u16*)(ws + (17ull << 20));        // 64 MB @ 17 MB

  const size_t NEED1 = (81ull << 20);
  const size_t NEED0 = (17ull << 20);

  hipMemsetAsync(ws, 0, 1u << 20, stream);   // zero h0/h1/flags/cbuf every launch

  if (ws_size >= NEED0) {
    {
      const int n8 = (int)((size_t)GG * DD / 8);
      conv_wih_kernel<<<(n8 + 255) / 256, 256, 0, stream>>>(W_ih, wihb);
    }
    if (ws_size >= NEED1) {
      const int n8 = (int)((size_t)BB * TT * DD / 8);
      conv_xT_kernel<<<(n8 + 255) / 256, 256, 0, stream>>>(x, xbT);
      lstm_persistent<1><<<256, 512, 0, stream>>>(x, xbT, wihb, W_hh, b_ih, b_hh, h0, h1, arrv, gof);
    } else {
      lstm_persistent<0><<<256, 512, 0, stream>>>(x, xbT, wihb, W_hh, b_ih, b_hh, h0, h1, arrv, gof);
    }
  } else {
    for (int t = 0; t < TT; ++t) {
      u16* hs = (t & 1) ? h1 : h0;
      u16* hd = (t & 1) ? h0 : h1;
      lstm_step_kernel<<<256, 512, 0, stream>>>(x, W_ih, W_hh, b_ih, b_hh, hs, hd, cbuf, t);
    }
  }

  // t=511 (odd) -> final h in h0
  head_kernel<<<64, 256, 0, stream>>>(h0, W_head, b_head, out);
}